// Round 3
// baseline (420.050 us; speedup 1.0000x reference)
//
#include <hip/hip_runtime.h>
#include <hip/hip_bf16.h>

// Problem: B=2, T=2048, C=2048, NQ=16, NKV=4, H=128, EPS=1e-6
// DTYPE GROUND TRUTH (established rounds 1-6): ALL inputs f32, output f32.
// Internals: bf16 (weights pre-converted; x converted during LDS staging).
#define B_   2
#define T_   2048
#define C_   2048
#define NQ_  16
#define NKV_ 4
#define H_   128

using bf16x8 = __attribute__((ext_vector_type(8))) short;
using f32x4  = __attribute__((ext_vector_type(4))) float;

__device__ __forceinline__ unsigned short f2bf(float f) {
    __hip_bfloat16 h = __float2bfloat16(f);  // RNE
    union { __hip_bfloat16 h; unsigned short s; } c;
    c.h = h;
    return c.s;
}
__device__ __forceinline__ float bf2f(unsigned short s) {
    return __uint_as_float(((unsigned)s) << 16);
}
__device__ __forceinline__ bf16x8 pack8(float4 f0, float4 f1) {
    bf16x8 r;
    r[0] = (short)f2bf(f0.x); r[1] = (short)f2bf(f0.y);
    r[2] = (short)f2bf(f0.z); r[3] = (short)f2bf(f0.w);
    r[4] = (short)f2bf(f1.x); r[5] = (short)f2bf(f1.y);
    r[6] = (short)f2bf(f1.z); r[7] = (short)f2bf(f1.w);
    return r;
}

#define MFMA16(a, b, c) __builtin_amdgcn_mfma_f32_16x16x32_bf16(a, b, c, 0, 0, 0)

// ---------------------------------------------------------------------------
// 64x64-tile transpose + f32->bf16 convert: dst[c][r] = bf16(src[r][c]).
// ---------------------------------------------------------------------------
__global__ void transpose_cvt(const float* __restrict__ src,
                              unsigned short* __restrict__ dst,
                              int R, int Cc) {
    const int tc = Cc >> 6;
    const int r0 = (blockIdx.x / tc) * 64;
    const int c0 = (blockIdx.x % tc) * 64;
    __shared__ unsigned short Tl[64 * 65];
    const int tid = threadIdx.x;
#pragma unroll
    for (int it = 0; it < 16; ++it) {
        const int idx = it * 256 + tid;
        const int r = idx >> 6, c = idx & 63;
        Tl[c * 65 + r] = f2bf(src[(size_t)(r0 + r) * Cc + c0 + c]);
    }
    __syncthreads();
#pragma unroll
    for (int it = 0; it < 16; ++it) {
        const int idx = it * 256 + tid;
        const int c = idx >> 6, r = idx & 63;
        dst[(size_t)(c0 + c) * R + r0 + r] = Tl[c * 65 + r];
    }
}

// ---------------------------------------------------------------------------
// 128x128-tile GEMM (unchanged — verified): C = A @ Bt^T.
// ---------------------------------------------------------------------------
#define LDP 40

template <bool A_BF, bool OUT_F32>
__global__ __launch_bounds__(256, 2) void gemm_bt(
    const void* __restrict__ Av,
    const unsigned short* __restrict__ Bt,
    void* __restrict__ Cqv,
    unsigned short* __restrict__ Ck,
    unsigned short* __restrict__ Cv,
    int M, int N, int K, int fused) {
    const int ntn = N >> 7;
    const int tm  = blockIdx.x / ntn;
    const int tn  = blockIdx.x % ntn;

    const int tid  = threadIdx.x;
    const int wv   = tid >> 6;
    const int lane = tid & 63;
    const int col  = lane & 15;
    const int quad = lane >> 4;
    const int wm   = (wv & 1) * 64;
    const int wn   = (wv >> 1) * 64;

    __shared__ unsigned short Al[128 * LDP];
    __shared__ unsigned short Bl[128 * LDP];

    f32x4 acc[4][4];
#pragma unroll
    for (int mt = 0; mt < 4; ++mt)
#pragma unroll
        for (int nt = 0; nt < 4; ++nt) acc[mt][nt] = (f32x4){0.f, 0.f, 0.f, 0.f};

    const int i1 = tid, i2 = tid + 256;
    const size_t aoff1 = (size_t)(tm * 128 + (i1 >> 2)) * K + (i1 & 3) * 8;
    const size_t aoff2 = (size_t)(tm * 128 + (i2 >> 2)) * K + (i2 & 3) * 8;
    const size_t boff1 = (size_t)(tn * 128 + (i1 >> 2)) * K + (i1 & 3) * 8;
    const size_t boff2 = (size_t)(tn * 128 + (i2 >> 2)) * K + (i2 & 3) * 8;
    unsigned short* Aw1 = Al + (i1 >> 2) * LDP + (i1 & 3) * 8;
    unsigned short* Aw2 = Al + (i2 >> 2) * LDP + (i2 & 3) * 8;
    unsigned short* Bw1 = Bl + (i1 >> 2) * LDP + (i1 & 3) * 8;
    unsigned short* Bw2 = Bl + (i2 >> 2) * LDP + (i2 & 3) * 8;

    const unsigned short* Ab16 = (const unsigned short*)Av;
    const float*          Af   = (const float*)Av;

    uint4  a1u, a2u, b1u, b2u;
    float4 a1lo, a1hi, a2lo, a2hi;

    auto loadAB = [&](int kk) {
        if constexpr (A_BF) {
            a1u = *(const uint4*)(Ab16 + aoff1 + kk);
            a2u = *(const uint4*)(Ab16 + aoff2 + kk);
        } else {
            a1lo = *(const float4*)(Af + aoff1 + kk);
            a1hi = *(const float4*)(Af + aoff1 + kk + 4);
            a2lo = *(const float4*)(Af + aoff2 + kk);
            a2hi = *(const float4*)(Af + aoff2 + kk + 4);
        }
        b1u = *(const uint4*)(Bt + boff1 + kk);
        b2u = *(const uint4*)(Bt + boff2 + kk);
    };

    loadAB(0);

    for (int k0 = 0; k0 < K; k0 += 32) {
        __syncthreads();
        if constexpr (A_BF) {
            *(uint4*)Aw1 = a1u;
            *(uint4*)Aw2 = a2u;
        } else {
            *(bf16x8*)Aw1 = pack8(a1lo, a1hi);
            *(bf16x8*)Aw2 = pack8(a2lo, a2hi);
        }
        *(uint4*)Bw1 = b1u;
        *(uint4*)Bw2 = b2u;
        __syncthreads();

        const int kn = (k0 + 32 < K) ? k0 + 32 : k0;
        loadAB(kn);

        bf16x8 af[4], bfv[4];
#pragma unroll
        for (int t = 0; t < 4; ++t) {
            af[t]  = *(const bf16x8*)(Al + (wm + t * 16 + col) * LDP + quad * 8);
            bfv[t] = *(const bf16x8*)(Bl + (wn + t * 16 + col) * LDP + quad * 8);
        }
#pragma unroll
        for (int mt = 0; mt < 4; ++mt)
#pragma unroll
            for (int nt = 0; nt < 4; ++nt)
                acc[mt][nt] = MFMA16(af[mt], bfv[nt], acc[mt][nt]);
    }

    const int nb = tn * 128;
    if constexpr (OUT_F32) {
        float* Co = (float*)Cqv;
#pragma unroll
        for (int mt = 0; mt < 4; ++mt)
#pragma unroll
            for (int nt = 0; nt < 4; ++nt)
#pragma unroll
                for (int r = 0; r < 4; ++r) {
                    const int row = tm * 128 + wm + mt * 16 + quad * 4 + r;
                    const int cc  = nb + wn + nt * 16 + col;
                    Co[(size_t)row * N + cc] = acc[mt][nt][r];
                }
    } else {
        unsigned short* Cb;
        int ldc, nc0;
        if (!fused)         { Cb = (unsigned short*)Cqv; ldc = N;    nc0 = nb;        }
        else if (nb < 2048) { Cb = (unsigned short*)Cqv; ldc = 2048; nc0 = nb;        }
        else if (nb < 2560) { Cb = Ck;                   ldc = 512;  nc0 = nb - 2048; }
        else                { Cb = Cv;                   ldc = 512;  nc0 = nb - 2560; }
#pragma unroll
        for (int mt = 0; mt < 4; ++mt)
#pragma unroll
            for (int nt = 0; nt < 4; ++nt)
#pragma unroll
                for (int r = 0; r < 4; ++r) {
                    const int row = tm * 128 + wm + mt * 16 + quad * 4 + r;
                    const int cc  = nc0 + wn + nt * 16 + col;
                    Cb[(size_t)row * ldc + cc] = f2bf(acc[mt][nt][r]);
                }
    }
}

// ---------------------------------------------------------------------------
// Fused per-head RMSNorm + RoPE. oscale folds log2(e)/sqrt(H) into Q so the
// flash kernel's scores come out pre-scaled for the exp2-domain softmax.
// ---------------------------------------------------------------------------
__global__ void norm_rope(unsigned short* __restrict__ buf,
                          const float* __restrict__ w,
                          const float* __restrict__ cosb,
                          const float* __restrict__ sinb,
                          int nheads, float oscale) {
    const int idx = blockIdx.x;
    const int h   = idx % nheads;
    const int bt  = idx / nheads;
    const int t   = bt % T_;
    unsigned short* row = buf + ((size_t)bt * nheads + h) * H_;
    const int l = threadIdx.x;  // 0..63

    const float x0 = bf2f(row[l]);
    const float x1 = bf2f(row[l + 64]);
    float ss = x0 * x0 + x1 * x1;
#pragma unroll
    for (int off = 32; off; off >>= 1) ss += __shfl_xor(ss, off);
    const float r = rsqrtf(ss * (1.0f / 128.0f) + 1e-6f) * oscale;

    const float n0 = x0 * r * w[l];
    const float n1 = x1 * r * w[l + 64];
    const float c0 = cosb[t * H_ + l];
    const float c1 = cosb[t * H_ + l + 64];
    const float s0 = sinb[t * H_ + l];
    const float s1 = sinb[t * H_ + l + 64];

    row[l]      = f2bf(n0 * c0 - n1 * s0);
    row[l + 64] = f2bf(n1 * c1 + n0 * s1);
}

// ---------------------------------------------------------------------------
// MFMA flash attention v4: v3 + async-STAGE split (T14, 1-chunk prefetch).
//   Loop: barrier A -> write regs->LDS (chunk c) -> barrier B ->
//         issue global loads (chunk c+1) -> compute c.
//   At barrier B zero vmem is outstanding; at barrier A the prefetched loads
//   have had the whole compute phase to land -> __syncthreads' vmcnt(0)
//   drain is ~free. K keeps the XOR-swizzled granule layout (swizzle moved
//   to the ds_write side); V keeps the packed-transpose [d][72] layout.
//   Swapped QK^T + in-lane softmax + defer-max as in v3.
// LDS = 16384 + 18432 + 18432 + 512 = 53760 B.
// ---------------------------------------------------------------------------
__global__ __launch_bounds__(256, 2) void flash_attn(
    const unsigned short* __restrict__ qbuf,
    const unsigned short* __restrict__ kbuf,
    const unsigned short* __restrict__ vbuf,
    unsigned short* __restrict__ ctx) {
    const int blk = blockIdx.x;                 // 512 blocks
    const int lo  = blk & 15;
    const int bh  = blk >> 4;                   // 0..31
    const int qt  = (bh & 16) ? (15 - lo) : lo; // flip pairing: balance work
    const int h   = bh & 15;
    const int b   = bh >> 4;
    const int kvh = h >> 2;

    const int tid  = threadIdx.x;
    const int wave = tid >> 6;
    const int lane = tid & 63;
    const int col  = lane & 15;
    const int quad = lane >> 4;

    const int qbase = qt * 128;
    const int w0    = qbase + wave * 32;

    __shared__ unsigned short Kl[64 * 128];   // linear rows, XOR-swizzled granules
    __shared__ unsigned short Vt[128 * 72];   // V^T, straight key order
    __shared__ unsigned short Pl[4][32 * 72]; // per-wave P, straight key order
    __shared__ float alf[4][32];              // per-wave alpha / inv-l broadcast

    // Q fragments (y-operand rows = queries), pre-scaled by log2(e)/sqrt(H)
    bf16x8 qf[2][4];
#pragma unroll
    for (int nt = 0; nt < 2; ++nt)
#pragma unroll
        for (int ks = 0; ks < 4; ++ks) {
            const size_t off =
                ((size_t)(b * T_ + w0 + nt * 16 + col) * NQ_ + h) * H_ + ks * 32 + quad * 8;
            qf[nt][ks] = *(const bf16x8*)(qbuf + off);
        }

    f32x4 O[2][8];
#pragma unroll
    for (int pt = 0; pt < 2; ++pt)
#pragma unroll
        for (int dt = 0; dt < 8; ++dt) O[pt][dt] = (f32x4){0.f, 0.f, 0.f, 0.f};
    float m_run[2] = {-3.0e38f, -3.0e38f};
    float l_run[2] = {0.f, 0.f};

    const int swb = (col & 7) << 4;        // K read swizzle (bytes)
    unsigned short* Pw = Pl[wave];
    unsigned* Vw = (unsigned*)Vt;
    const int nch = 2 * qt + 2;            // chunks of 64 keys

    // ---- staging register state (T14: issue-early / write-late) ----
    uint4 ka[4], va[4];
    const size_t kvstride = (size_t)NKV_ * H_;  // one key row

    auto issueK = [&](int j0) {
#pragma unroll
        for (int i = 0; i < 4; ++i) {
            const int row = wave * 16 + i * 4 + quad;            // 0..63
            ka[i] = *(const uint4*)(
                kbuf + ((size_t)(b * T_ + j0 + row) * NKV_ + kvh) * H_ +
                ((col ^ (row & 7)) << 3));                       // swizzled 16B granule
        }
    };
    auto issueV = [&](int j0) {
#pragma unroll
        for (int it = 0; it < 2; ++it) {
            const int idx = it * 256 + tid;  // 0..511
            const int kp  = idx & 31;        // key pair 0..31
            const int dc  = idx >> 5;        // 0..15 (8-dim chunk)
            const size_t g0 = ((size_t)(b * T_ + j0 + 2 * kp) * NKV_ + kvh) * H_ + dc * 8;
            va[2 * it]     = *(const uint4*)(vbuf + g0);
            va[2 * it + 1] = *(const uint4*)(vbuf + g0 + kvstride);
        }
    };
    auto writeK = [&]() {
#pragma unroll
        for (int i = 0; i < 4; ++i) {
            const int row = wave * 16 + i * 4 + quad;
            *(uint4*)(Kl + row * 128 + col * 8) = ka[i];
        }
    };
    auto writeV = [&]() {
#pragma unroll
        for (int it = 0; it < 2; ++it) {
            const int idx = it * 256 + tid;
            const int kp  = idx & 31;
            const int dc  = idx >> 5;
            const uint4 v0 = va[2 * it];
            const uint4 v1 = va[2 * it + 1];
            const int wb = dc * 288 + kp;  // u32 index: rows dc*8..dc*8+7, keys 2kp,2kp+1
            Vw[wb + 0 * 36] = (v0.x & 0xFFFFu) | (v1.x << 16);
            Vw[wb + 1 * 36] = (v0.x >> 16)     | (v1.x & 0xFFFF0000u);
            Vw[wb + 2 * 36] = (v0.y & 0xFFFFu) | (v1.y << 16);
            Vw[wb + 3 * 36] = (v0.y >> 16)     | (v1.y & 0xFFFF0000u);
            Vw[wb + 4 * 36] = (v0.z & 0xFFFFu) | (v1.z << 16);
            Vw[wb + 5 * 36] = (v0.z >> 16)     | (v1.z & 0xFFFF0000u);
            Vw[wb + 6 * 36] = (v0.w & 0xFFFFu) | (v1.w << 16);
            Vw[wb + 7 * 36] = (v0.w >> 16)     | (v1.w & 0xFFFF0000u);
        }
    };

    issueK(0);
    issueV(0);

    for (int c = 0; c < nch; ++c) {
        const int j0 = c * 64;
        __syncthreads();  // A: prior chunk's LDS reads complete; prefetched loads landed
        writeK();
        writeV();
        __syncthreads();  // B: staged tiles visible (no vmem outstanding here)

        if (c + 1 < nch) {             // prefetch next chunk under this chunk's compute
            issueK(j0 + 64);
            issueV(j0 + 64);
        }

        if (j0 > w0 + 31) continue;  // done computing; still stages each iter

        // ---- swapped QK^T: St[key-tile][q-tile], 32 MFMAs ----
        f32x4 St[4][2];
#pragma unroll
        for (int mt = 0; mt < 4; ++mt)
#pragma unroll
            for (int nt = 0; nt < 2; ++nt) St[mt][nt] = (f32x4){0.f, 0.f, 0.f, 0.f};
#pragma unroll
        for (int ks = 0; ks < 4; ++ks)
#pragma unroll
            for (int mt = 0; mt < 4; ++mt) {
                const bf16x8 kfrag = *(const bf16x8*)(
                    Kl + ((mt * 16 + col) << 7) + (((ks * 64 + quad * 16) ^ swb) >> 1));
                St[mt][0] = MFMA16(kfrag, qf[0][ks], St[mt][0]);
                St[mt][1] = MFMA16(kfrag, qf[1][ks], St[mt][1]);
            }

        // ---- mask (acc row = key, col = query) ----
        const bool needmask = (j0 + 63 > w0);
        if (needmask) {
            const int ig0 = w0 + col;
#pragma unroll
            for (int mt = 0; mt < 4; ++mt)
#pragma unroll
                for (int r = 0; r < 4; ++r) {
                    const int key = j0 + mt * 16 + quad * 4 + r;
                    if (key > ig0)      St[mt][0][r] = -3.0e38f;
                    if (key > ig0 + 16) St[mt][1][r] = -3.0e38f;
                }
        }

        // ---- in-lane row max (keys are the reg/quad axis) ----
        float rm[2];
#pragma unroll
        for (int nt = 0; nt < 2; ++nt) {
            float m0 = fmaxf(fmaxf(St[0][nt][0], St[0][nt][1]),
                             fmaxf(St[0][nt][2], St[0][nt][3]));
#pragma unroll
            for (int mt = 1; mt < 4; ++mt)
                m0 = fmaxf(m0, fmaxf(fmaxf(St[mt][nt][0], St[mt][nt][1]),
                                     fmaxf(St[mt][nt][2], St[mt][nt][3])));
            m0 = fmaxf(m0, __shfl_xor(m0, 16));
            m0 = fmaxf(m0, __shfl_xor(m0, 32));
            rm[nt] = m0;
        }

        // ---- defer-max: skip rescale unless max grew > 8 (exp2 domain) ----
        const int defer = __all((rm[0] <= m_run[0] + 8.0f) && (rm[1] <= m_run[1] + 8.0f));
        if (!defer) {
            const float mn0 = fmaxf(m_run[0], rm[0]);
            const float mn1 = fmaxf(m_run[1], rm[1]);
            const float al0 = exp2f(m_run[0] - mn0);
            const float al1 = exp2f(m_run[1] - mn1);
            m_run[0] = mn0; m_run[1] = mn1;
            l_run[0] *= al0; l_run[1] *= al1;
            if (quad == 0) { alf[wave][col] = al0; alf[wave][col + 16] = al1; }
        }

        // ---- P = exp2(S - m), in-lane sum, b64 packed writes (straight) ----
        float ls0 = 0.f, ls1 = 0.f;
#pragma unroll
        for (int mt = 0; mt < 4; ++mt) {
            const float p0 = exp2f(St[mt][0][0] - m_run[0]);
            const float p1 = exp2f(St[mt][0][1] - m_run[0]);
            const float p2 = exp2f(St[mt][0][2] - m_run[0]);
            const float p3 = exp2f(St[mt][0][3] - m_run[0]);
            ls0 += (p0 + p1) + (p2 + p3);
            *(uint2*)(Pw + col * 72 + mt * 16 + quad * 4) =
                make_uint2((unsigned)f2bf(p0) | ((unsigned)f2bf(p1) << 16),
                           (unsigned)f2bf(p2) | ((unsigned)f2bf(p3) << 16));
            const float q0 = exp2f(St[mt][1][0] - m_run[1]);
            const float q1 = exp2f(St[mt][1][1] - m_run[1]);
            const float q2 = exp2f(St[mt][1][2] - m_run[1]);
            const float q3 = exp2f(St[mt][1][3] - m_run[1]);
            ls1 += (q0 + q1) + (q2 + q3);
            *(uint2*)(Pw + (col + 16) * 72 + mt * 16 + quad * 4) =
                make_uint2((unsigned)f2bf(q0) | ((unsigned)f2bf(q1) << 16),
                           (unsigned)f2bf(q2) | ((unsigned)f2bf(q3) << 16));
        }
        ls0 += __shfl_xor(ls0, 16); ls0 += __shfl_xor(ls0, 32);
        ls1 += __shfl_xor(ls1, 16); ls1 += __shfl_xor(ls1, 32);
        l_run[0] += ls0; l_run[1] += ls1;

        // ---- O rescale via per-wave alpha broadcast (only when not deferred) ----
        if (!defer) {
            const f32x4 a0 = *(const f32x4*)&alf[wave][quad * 4];
            const f32x4 a1 = *(const f32x4*)&alf[wave][quad * 4 + 16];
#pragma unroll
            for (int dt = 0; dt < 8; ++dt)
#pragma unroll
                for (int r = 0; r < 4; ++r) { O[0][dt][r] *= a0[r]; O[1][dt][r] *= a1[r]; }
        }

        // ---- PV: O += P(32x64) @ V(64x128), 32 MFMAs ----
#pragma unroll
        for (int ks = 0; ks < 2; ++ks) {
            const bf16x8 pa0 = *(const bf16x8*)(Pw + col * 72 + ks * 32 + quad * 8);
            const bf16x8 pa1 = *(const bf16x8*)(Pw + (col + 16) * 72 + ks * 32 + quad * 8);
#pragma unroll
            for (int dt = 0; dt < 8; ++dt) {
                const bf16x8 vf = *(const bf16x8*)(Vt + (dt * 16 + col) * 72 + ks * 32 + quad * 8);
                O[0][dt] = MFMA16(pa0, vf, O[0][dt]);
                O[1][dt] = MFMA16(pa1, vf, O[1][dt]);
            }
        }
    }

    // ---- epilogue: inv-l broadcast, normalize, store ----
    if (quad == 0) {
        alf[wave][col]      = 1.0f / l_run[0];
        alf[wave][col + 16] = 1.0f / l_run[1];
    }
    const f32x4 i0 = *(const f32x4*)&alf[wave][quad * 4];
    const f32x4 i1 = *(const f32x4*)&alf[wave][quad * 4 + 16];
#pragma unroll
    for (int pt = 0; pt < 2; ++pt)
#pragma unroll
        for (int r = 0; r < 4; ++r) {
            const float inv = pt ? i1[r] : i0[r];
            const int ig = w0 + pt * 16 + quad * 4 + r;
            unsigned short* op = ctx + ((size_t)(b * T_ + ig) * NQ_ + h) * H_;
#pragma unroll
            for (int dt = 0; dt < 8; ++dt)
                op[dt * 16 + col] = f2bf(O[pt][dt][r] * inv);
        }
}

// ---------------------------------------------------------------------------
extern "C" void kernel_launch(void* const* d_in, const int* in_sizes, int n_in,
                              void* d_out, int out_size, void* d_ws, size_t ws_size,
                              hipStream_t stream) {
    const float* x    = (const float*)d_in[0];
    const float* Wq   = (const float*)d_in[1];
    const float* Wk   = (const float*)d_in[2];
    const float* Wv   = (const float*)d_in[3];
    const float* Wo   = (const float*)d_in[4];
    const float* qnw  = (const float*)d_in[5];
    const float* knw  = (const float*)d_in[6];
    const float* cosb = (const float*)d_in[7];
    const float* sinb = (const float*)d_in[8];
    // d_in[9] = attn_mask: exact causal tril(0/-1e9) -> implemented directly

    const int M = B_ * T_;  // 4096
    // ws layout (u16 offsets), 42 MB proven footprint:
    //   WqT/WkT/WvT [0,6291456) dead after QKV; ctx [0,8388608) aliases them
    //   q [8388608,16777216) (WoT aliases after attn); k; v
    unsigned short* ws  = (unsigned short*)d_ws;
    unsigned short* WqT = ws;
    unsigned short* WkT = WqT + (size_t)2048 * 2048;
    unsigned short* WvT = WkT + (size_t)512 * 2048;
    unsigned short* ctx = ws;
    unsigned short* q   = ws + (size_t)8388608;
    unsigned short* k   = ws + (size_t)16777216;
    unsigned short* v   = ws + (size_t)18874368;
    unsigned short* WoT = q;

    transpose_cvt<<<(2048 / 64) * (2048 / 64), 256, 0, stream>>>(Wq, WqT, 2048, 2048);
    transpose_cvt<<<(2048 / 64) * (512 / 64),  256, 0, stream>>>(Wk, WkT, 2048, 512);
    transpose_cvt<<<(2048 / 64) * (512 / 64),  256, 0, stream>>>(Wv, WvT, 2048, 512);

    gemm_bt<false, false><<<(M / 128) * (3072 / 128), 256, 0, stream>>>(
        (const void*)x, WqT, (void*)q, k, v, M, 3072, C_, 1);

    // Q pre-scaled by log2(e)/sqrt(128) for the exp2-domain softmax
    norm_rope<<<M * NQ_, 64, 0, stream>>>(q, qnw, cosb, sinb, NQ_, 0.12751743f);
    norm_rope<<<M * NKV_, 64, 0, stream>>>(k, knw, cosb, sinb, NKV_, 1.0f);

    flash_attn<<<512, 256, 0, stream>>>(q, k, v, ctx);

    transpose_cvt<<<(2048 / 64) * (2048 / 64), 256, 0, stream>>>(Wo, WoT, 2048, 2048);
    gemm_bt<true, true><<<(M / 128) * (C_ / 128), 256, 0, stream>>>(
        (const void*)ctx, WoT, d_out, nullptr, nullptr, M, C_, NQ_ * H_, 0);
}

// Round 4
// 396.183 us; speedup vs baseline: 1.0602x; 1.0602x over previous
//
#include <hip/hip_runtime.h>
#include <hip/hip_bf16.h>

// Problem: B=2, T=2048, C=2048, NQ=16, NKV=4, H=128, EPS=1e-6
// DTYPE GROUND TRUTH (established rounds 1-6): ALL inputs f32, output f32.
// Internals: bf16 (weights pre-converted; x converted during LDS staging).
#define B_   2
#define T_   2048
#define C_   2048
#define NQ_  16
#define NKV_ 4
#define H_   128

using bf16x8 = __attribute__((ext_vector_type(8))) short;
using f32x4  = __attribute__((ext_vector_type(4))) float;

__device__ __forceinline__ unsigned short f2bf(float f) {
    __hip_bfloat16 h = __float2bfloat16(f);  // RNE
    union { __hip_bfloat16 h; unsigned short s; } c;
    c.h = h;
    return c.s;
}
__device__ __forceinline__ float bf2f(unsigned short s) {
    return __uint_as_float(((unsigned)s) << 16);
}
__device__ __forceinline__ bf16x8 pack8(float4 f0, float4 f1) {
    bf16x8 r;
    r[0] = (short)f2bf(f0.x); r[1] = (short)f2bf(f0.y);
    r[2] = (short)f2bf(f0.z); r[3] = (short)f2bf(f0.w);
    r[4] = (short)f2bf(f1.x); r[5] = (short)f2bf(f1.y);
    r[6] = (short)f2bf(f1.z); r[7] = (short)f2bf(f1.w);
    return r;
}

#define MFMA16(a, b, c) __builtin_amdgcn_mfma_f32_16x16x32_bf16(a, b, c, 0, 0, 0)

// ---------------------------------------------------------------------------
// 64x64-tile transpose + f32->bf16 convert: dst[c][r] = bf16(src[r][c]).
// ---------------------------------------------------------------------------
__global__ void transpose_cvt(const float* __restrict__ src,
                              unsigned short* __restrict__ dst,
                              int R, int Cc) {
    const int tc = Cc >> 6;
    const int r0 = (blockIdx.x / tc) * 64;
    const int c0 = (blockIdx.x % tc) * 64;
    __shared__ unsigned short Tl[64 * 65];
    const int tid = threadIdx.x;
#pragma unroll
    for (int it = 0; it < 16; ++it) {
        const int idx = it * 256 + tid;
        const int r = idx >> 6, c = idx & 63;
        Tl[c * 65 + r] = f2bf(src[(size_t)(r0 + r) * Cc + c0 + c]);
    }
    __syncthreads();
#pragma unroll
    for (int it = 0; it < 16; ++it) {
        const int idx = it * 256 + tid;
        const int c = idx >> 6, r = idx & 63;
        dst[(size_t)(c0 + c) * R + r0 + r] = Tl[c * 65 + r];
    }
}

// ---------------------------------------------------------------------------
// 128x128-tile GEMM (unchanged — verified): C = A @ Bt^T.
// ---------------------------------------------------------------------------
#define LDP 40

template <bool A_BF, bool OUT_F32>
__global__ __launch_bounds__(256, 2) void gemm_bt(
    const void* __restrict__ Av,
    const unsigned short* __restrict__ Bt,
    void* __restrict__ Cqv,
    unsigned short* __restrict__ Ck,
    unsigned short* __restrict__ Cv,
    int M, int N, int K, int fused) {
    const int ntn = N >> 7;
    const int tm  = blockIdx.x / ntn;
    const int tn  = blockIdx.x % ntn;

    const int tid  = threadIdx.x;
    const int wv   = tid >> 6;
    const int lane = tid & 63;
    const int col  = lane & 15;
    const int quad = lane >> 4;
    const int wm   = (wv & 1) * 64;
    const int wn   = (wv >> 1) * 64;

    __shared__ unsigned short Al[128 * LDP];
    __shared__ unsigned short Bl[128 * LDP];

    f32x4 acc[4][4];
#pragma unroll
    for (int mt = 0; mt < 4; ++mt)
#pragma unroll
        for (int nt = 0; nt < 4; ++nt) acc[mt][nt] = (f32x4){0.f, 0.f, 0.f, 0.f};

    const int i1 = tid, i2 = tid + 256;
    const size_t aoff1 = (size_t)(tm * 128 + (i1 >> 2)) * K + (i1 & 3) * 8;
    const size_t aoff2 = (size_t)(tm * 128 + (i2 >> 2)) * K + (i2 & 3) * 8;
    const size_t boff1 = (size_t)(tn * 128 + (i1 >> 2)) * K + (i1 & 3) * 8;
    const size_t boff2 = (size_t)(tn * 128 + (i2 >> 2)) * K + (i2 & 3) * 8;
    unsigned short* Aw1 = Al + (i1 >> 2) * LDP + (i1 & 3) * 8;
    unsigned short* Aw2 = Al + (i2 >> 2) * LDP + (i2 & 3) * 8;
    unsigned short* Bw1 = Bl + (i1 >> 2) * LDP + (i1 & 3) * 8;
    unsigned short* Bw2 = Bl + (i2 >> 2) * LDP + (i2 & 3) * 8;

    const unsigned short* Ab16 = (const unsigned short*)Av;
    const float*          Af   = (const float*)Av;

    uint4  a1u, a2u, b1u, b2u;
    float4 a1lo, a1hi, a2lo, a2hi;

    auto loadAB = [&](int kk) {
        if constexpr (A_BF) {
            a1u = *(const uint4*)(Ab16 + aoff1 + kk);
            a2u = *(const uint4*)(Ab16 + aoff2 + kk);
        } else {
            a1lo = *(const float4*)(Af + aoff1 + kk);
            a1hi = *(const float4*)(Af + aoff1 + kk + 4);
            a2lo = *(const float4*)(Af + aoff2 + kk);
            a2hi = *(const float4*)(Af + aoff2 + kk + 4);
        }
        b1u = *(const uint4*)(Bt + boff1 + kk);
        b2u = *(const uint4*)(Bt + boff2 + kk);
    };

    loadAB(0);

    for (int k0 = 0; k0 < K; k0 += 32) {
        __syncthreads();
        if constexpr (A_BF) {
            *(uint4*)Aw1 = a1u;
            *(uint4*)Aw2 = a2u;
        } else {
            *(bf16x8*)Aw1 = pack8(a1lo, a1hi);
            *(bf16x8*)Aw2 = pack8(a2lo, a2hi);
        }
        *(uint4*)Bw1 = b1u;
        *(uint4*)Bw2 = b2u;
        __syncthreads();

        const int kn = (k0 + 32 < K) ? k0 + 32 : k0;
        loadAB(kn);

        bf16x8 af[4], bfv[4];
#pragma unroll
        for (int t = 0; t < 4; ++t) {
            af[t]  = *(const bf16x8*)(Al + (wm + t * 16 + col) * LDP + quad * 8);
            bfv[t] = *(const bf16x8*)(Bl + (wn + t * 16 + col) * LDP + quad * 8);
        }
#pragma unroll
        for (int mt = 0; mt < 4; ++mt)
#pragma unroll
            for (int nt = 0; nt < 4; ++nt)
                acc[mt][nt] = MFMA16(af[mt], bfv[nt], acc[mt][nt]);
    }

    const int nb = tn * 128;
    if constexpr (OUT_F32) {
        float* Co = (float*)Cqv;
#pragma unroll
        for (int mt = 0; mt < 4; ++mt)
#pragma unroll
            for (int nt = 0; nt < 4; ++nt)
#pragma unroll
                for (int r = 0; r < 4; ++r) {
                    const int row = tm * 128 + wm + mt * 16 + quad * 4 + r;
                    const int cc  = nb + wn + nt * 16 + col;
                    Co[(size_t)row * N + cc] = acc[mt][nt][r];
                }
    } else {
        unsigned short* Cb;
        int ldc, nc0;
        if (!fused)         { Cb = (unsigned short*)Cqv; ldc = N;    nc0 = nb;        }
        else if (nb < 2048) { Cb = (unsigned short*)Cqv; ldc = 2048; nc0 = nb;        }
        else if (nb < 2560) { Cb = Ck;                   ldc = 512;  nc0 = nb - 2048; }
        else                { Cb = Cv;                   ldc = 512;  nc0 = nb - 2560; }
#pragma unroll
        for (int mt = 0; mt < 4; ++mt)
#pragma unroll
            for (int nt = 0; nt < 4; ++nt)
#pragma unroll
                for (int r = 0; r < 4; ++r) {
                    const int row = tm * 128 + wm + mt * 16 + quad * 4 + r;
                    const int cc  = nc0 + wn + nt * 16 + col;
                    Cb[(size_t)row * ldc + cc] = f2bf(acc[mt][nt][r]);
                }
    }
}

// ---------------------------------------------------------------------------
// Fused per-head RMSNorm + RoPE. oscale folds log2(e)/sqrt(H) into Q so the
// flash kernel's scores come out pre-scaled for the exp2-domain softmax.
// ---------------------------------------------------------------------------
__global__ void norm_rope(unsigned short* __restrict__ buf,
                          const float* __restrict__ w,
                          const float* __restrict__ cosb,
                          const float* __restrict__ sinb,
                          int nheads, float oscale) {
    const int idx = blockIdx.x;
    const int h   = idx % nheads;
    const int bt  = idx / nheads;
    const int t   = bt % T_;
    unsigned short* row = buf + ((size_t)bt * nheads + h) * H_;
    const int l = threadIdx.x;  // 0..63

    const float x0 = bf2f(row[l]);
    const float x1 = bf2f(row[l + 64]);
    float ss = x0 * x0 + x1 * x1;
#pragma unroll
    for (int off = 32; off; off >>= 1) ss += __shfl_xor(ss, off);
    const float r = rsqrtf(ss * (1.0f / 128.0f) + 1e-6f) * oscale;

    const float n0 = x0 * r * w[l];
    const float n1 = x1 * r * w[l + 64];
    const float c0 = cosb[t * H_ + l];
    const float c1 = cosb[t * H_ + l + 64];
    const float s0 = sinb[t * H_ + l];
    const float s1 = sinb[t * H_ + l + 64];

    row[l]      = f2bf(n0 * c0 - n1 * s0);
    row[l + 64] = f2bf(n1 * c1 + n0 * s1);
}

// ---------------------------------------------------------------------------
// MFMA flash attention v5: intra-block KV-split + in-LDS merge.
//   One 512-thread block per tile-pair (p, 15-p): 256 blocks = 1/CU, 8 waves
//   resident for the whole kernel (2 waves/SIMD sustained).
//   Group A (waves 0-3): tile p chunks [0, 2p+2), store its ctx mid-loop,
//     then tile 15-p partial over chunks [17, 32-2p).
//   Group B (waves 4-7): tile 15-p over chunks [0, 17).
//   Both groups: exactly 17 lockstep iterations, own K/V LDS buffer each,
//   reg-staged (T14) prefetch 1 chunk deep. Final flash-combine of the
//   B-tile partials through LDS (exact in exp2 domain).
//   Per-chunk compute = verified v4 path (swapped QK^T, in-lane softmax,
//   defer-max, XOR-swizzled K, packed V^T).
// LDS = 32768(K) + 36864(V) + 36864(P) + 1024(alf) + 2048(ml) = 109568 B.
// ---------------------------------------------------------------------------
__global__ __launch_bounds__(512, 2) void flash_attn(
    const unsigned short* __restrict__ qbuf,
    const unsigned short* __restrict__ kbuf,
    const unsigned short* __restrict__ vbuf,
    unsigned short* __restrict__ ctx) {
    const int blk = blockIdx.x;            // 256 blocks
    const int p   = blk & 7;               // pair: tiles p and 15-p
    const int h   = (blk >> 3) & 15;
    const int b   = blk >> 7;
    const int kvh = h >> 2;
    const int qtB = 15 - p;

    const int tid  = threadIdx.x;
    const int wave = tid >> 6;             // 0..7
    const int g    = wave >> 2;            // 0 = group A, 1 = group B
    const int gw   = wave & 3;             // wave-in-group
    const int lane = tid & 63;
    const int col  = lane & 15;
    const int quad = lane >> 4;
    const int gtid = gw * 64 + lane;       // 0..255 within group

    int w0 = (g ? qtB : p) * 128 + gw * 32;   // active 32 q-rows
    const int ph1 = 2 * p + 2;                // group A's own-tile chunk count

    __shared__ __align__(16) unsigned char smem[109568];
    unsigned short* Kg   = (unsigned short*)smem + g * 8192;           // [64][128]
    unsigned short* Vg   = (unsigned short*)(smem + 32768) + g * 9216; // [128][72]
    unsigned short* Pw   = (unsigned short*)(smem + 69632) + wave * 2304; // [32][72]
    float*          alfw = (float*)(smem + 106496) + wave * 32;        // [32]
    unsigned*       Vw   = (unsigned*)Vg;

    // Q fragments for active rows, pre-scaled by log2(e)/sqrt(H)
    bf16x8 qf[2][4];
    auto loadQ = [&]() {
#pragma unroll
        for (int nt = 0; nt < 2; ++nt)
#pragma unroll
            for (int ks = 0; ks < 4; ++ks) {
                const size_t off =
                    ((size_t)(b * T_ + w0 + nt * 16 + col) * NQ_ + h) * H_ + ks * 32 + quad * 8;
                qf[nt][ks] = *(const bf16x8*)(qbuf + off);
            }
    };
    loadQ();

    f32x4 O[2][8];
#pragma unroll
    for (int pt = 0; pt < 2; ++pt)
#pragma unroll
        for (int dt = 0; dt < 8; ++dt) O[pt][dt] = (f32x4){0.f, 0.f, 0.f, 0.f};
    float m_run[2] = {-3.0e38f, -3.0e38f};
    float l_run[2] = {0.f, 0.f};

    const int swb = (col & 7) << 4;  // K read swizzle (bytes)

    // ---- staging register state (T14: issue-early / write-late) ----
    uint4 ka[4], va[4];
    const size_t kvstride = (size_t)NKV_ * H_;

    auto issueK = [&](int j0) {
#pragma unroll
        for (int i = 0; i < 4; ++i) {
            const int row = gw * 16 + i * 4 + quad;              // 0..63
            ka[i] = *(const uint4*)(
                kbuf + ((size_t)(b * T_ + j0 + row) * NKV_ + kvh) * H_ +
                ((col ^ (row & 7)) << 3));                       // swizzled 16B granule
        }
    };
    auto issueV = [&](int j0) {
#pragma unroll
        for (int it = 0; it < 2; ++it) {
            const int idx = it * 256 + gtid;  // 0..511
            const int kp  = idx & 31;
            const int dc  = idx >> 5;
            const size_t g0 = ((size_t)(b * T_ + j0 + 2 * kp) * NKV_ + kvh) * H_ + dc * 8;
            va[2 * it]     = *(const uint4*)(vbuf + g0);
            va[2 * it + 1] = *(const uint4*)(vbuf + g0 + kvstride);
        }
    };
    auto writeK = [&]() {
#pragma unroll
        for (int i = 0; i < 4; ++i) {
            const int row = gw * 16 + i * 4 + quad;
            *(uint4*)(Kg + row * 128 + col * 8) = ka[i];
        }
    };
    auto writeV = [&]() {
#pragma unroll
        for (int it = 0; it < 2; ++it) {
            const int idx = it * 256 + gtid;
            const int kp  = idx & 31;
            const int dc  = idx >> 5;
            const uint4 v0 = va[2 * it];
            const uint4 v1 = va[2 * it + 1];
            const int wb = dc * 288 + kp;
            Vw[wb + 0 * 36] = (v0.x & 0xFFFFu) | (v1.x << 16);
            Vw[wb + 1 * 36] = (v0.x >> 16)     | (v1.x & 0xFFFF0000u);
            Vw[wb + 2 * 36] = (v0.y & 0xFFFFu) | (v1.y << 16);
            Vw[wb + 3 * 36] = (v0.y >> 16)     | (v1.y & 0xFFFF0000u);
            Vw[wb + 4 * 36] = (v0.z & 0xFFFFu) | (v1.z << 16);
            Vw[wb + 5 * 36] = (v0.z >> 16)     | (v1.z & 0xFFFF0000u);
            Vw[wb + 6 * 36] = (v0.w & 0xFFFFu) | (v1.w << 16);
            Vw[wb + 7 * 36] = (v0.w >> 16)     | (v1.w & 0xFFFF0000u);
        }
    };

    // tile-A epilogue (group A only, no barriers inside)
    auto storeOut = [&]() {
        if (quad == 0) {
            alfw[col]      = 1.0f / l_run[0];
            alfw[col + 16] = 1.0f / l_run[1];
        }
        const f32x4 i0 = *(const f32x4*)&alfw[quad * 4];
        const f32x4 i1 = *(const f32x4*)&alfw[quad * 4 + 16];
#pragma unroll
        for (int pt = 0; pt < 2; ++pt)
#pragma unroll
            for (int r = 0; r < 4; ++r) {
                const float inv = pt ? i1[r] : i0[r];
                const int ig = w0 + pt * 16 + quad * 4 + r;
                unsigned short* op = ctx + ((size_t)(b * T_ + ig) * NQ_ + h) * H_;
#pragma unroll
                for (int dt = 0; dt < 8; ++dt)
                    op[dt * 16 + col] = f2bf(O[pt][dt][r] * inv);
            }
    };

    // group chunk schedule: B: 0..16; A: 0..ph1-1 (own), then 17..(31-2p) (B-partial)
    auto chunk_of = [&](int i) { return g ? i : (i < ph1 ? i : i + 15 - 2 * p); };

    issueK(0);
    issueV(0);

    for (int i = 0; i < 17; ++i) {
        const int j0 = chunk_of(i) * 64;
        __syncthreads();  // prior chunk's LDS reads complete; prefetched loads landed
        writeK();
        writeV();
        __syncthreads();  // staged tiles visible

        if (i + 1 < 17) {
            const int jn = chunk_of(i + 1) * 64;
            issueK(jn);
            issueV(jn);
        }

        // group A: transition from own tile to B-tile partial
        if (g == 0 && i == ph1) {
            storeOut();  // tile p is complete -> ctx
#pragma unroll
            for (int pt = 0; pt < 2; ++pt)
#pragma unroll
                for (int dt = 0; dt < 8; ++dt) O[pt][dt] = (f32x4){0.f, 0.f, 0.f, 0.f};
            m_run[0] = m_run[1] = -3.0e38f;
            l_run[0] = l_run[1] = 0.f;
            w0 = qtB * 128 + gw * 32;
            loadQ();
        }

        if (j0 > w0 + 31) continue;  // fully-masked chunk for these rows

        // ---- swapped QK^T: St[key-tile][q-tile], 32 MFMAs ----
        f32x4 St[4][2];
#pragma unroll
        for (int mt = 0; mt < 4; ++mt)
#pragma unroll
            for (int nt = 0; nt < 2; ++nt) St[mt][nt] = (f32x4){0.f, 0.f, 0.f, 0.f};
#pragma unroll
        for (int ks = 0; ks < 4; ++ks)
#pragma unroll
            for (int mt = 0; mt < 4; ++mt) {
                const bf16x8 kfrag = *(const bf16x8*)(
                    Kg + ((mt * 16 + col) << 7) + (((ks * 64 + quad * 16) ^ swb) >> 1));
                St[mt][0] = MFMA16(kfrag, qf[0][ks], St[mt][0]);
                St[mt][1] = MFMA16(kfrag, qf[1][ks], St[mt][1]);
            }

        // ---- mask (acc row = key, col = query) ----
        const bool needmask = (j0 + 63 > w0);
        if (needmask) {
            const int ig0 = w0 + col;
#pragma unroll
            for (int mt = 0; mt < 4; ++mt)
#pragma unroll
                for (int r = 0; r < 4; ++r) {
                    const int key = j0 + mt * 16 + quad * 4 + r;
                    if (key > ig0)      St[mt][0][r] = -3.0e38f;
                    if (key > ig0 + 16) St[mt][1][r] = -3.0e38f;
                }
        }

        // ---- in-lane row max ----
        float rm[2];
#pragma unroll
        for (int nt = 0; nt < 2; ++nt) {
            float m0 = fmaxf(fmaxf(St[0][nt][0], St[0][nt][1]),
                             fmaxf(St[0][nt][2], St[0][nt][3]));
#pragma unroll
            for (int mt = 1; mt < 4; ++mt)
                m0 = fmaxf(m0, fmaxf(fmaxf(St[mt][nt][0], St[mt][nt][1]),
                                     fmaxf(St[mt][nt][2], St[mt][nt][3])));
            m0 = fmaxf(m0, __shfl_xor(m0, 16));
            m0 = fmaxf(m0, __shfl_xor(m0, 32));
            rm[nt] = m0;
        }

        // ---- defer-max (THR=8, exp2 domain) ----
        const int defer = __all((rm[0] <= m_run[0] + 8.0f) && (rm[1] <= m_run[1] + 8.0f));
        if (!defer) {
            const float mn0 = fmaxf(m_run[0], rm[0]);
            const float mn1 = fmaxf(m_run[1], rm[1]);
            const float al0 = exp2f(m_run[0] - mn0);
            const float al1 = exp2f(m_run[1] - mn1);
            m_run[0] = mn0; m_run[1] = mn1;
            l_run[0] *= al0; l_run[1] *= al1;
            if (quad == 0) { alfw[col] = al0; alfw[col + 16] = al1; }
        }

        // ---- P = exp2(S - m), in-lane sum, b64 packed writes ----
        float ls0 = 0.f, ls1 = 0.f;
#pragma unroll
        for (int mt = 0; mt < 4; ++mt) {
            const float p0 = exp2f(St[mt][0][0] - m_run[0]);
            const float p1 = exp2f(St[mt][0][1] - m_run[0]);
            const float p2 = exp2f(St[mt][0][2] - m_run[0]);
            const float p3 = exp2f(St[mt][0][3] - m_run[0]);
            ls0 += (p0 + p1) + (p2 + p3);
            *(uint2*)(Pw + col * 72 + mt * 16 + quad * 4) =
                make_uint2((unsigned)f2bf(p0) | ((unsigned)f2bf(p1) << 16),
                           (unsigned)f2bf(p2) | ((unsigned)f2bf(p3) << 16));
            const float q0 = exp2f(St[mt][1][0] - m_run[1]);
            const float q1 = exp2f(St[mt][1][1] - m_run[1]);
            const float q2 = exp2f(St[mt][1][2] - m_run[1]);
            const float q3 = exp2f(St[mt][1][3] - m_run[1]);
            ls1 += (q0 + q1) + (q2 + q3);
            *(uint2*)(Pw + (col + 16) * 72 + mt * 16 + quad * 4) =
                make_uint2((unsigned)f2bf(q0) | ((unsigned)f2bf(q1) << 16),
                           (unsigned)f2bf(q2) | ((unsigned)f2bf(q3) << 16));
        }
        ls0 += __shfl_xor(ls0, 16); ls0 += __shfl_xor(ls0, 32);
        ls1 += __shfl_xor(ls1, 16); ls1 += __shfl_xor(ls1, 32);
        l_run[0] += ls0; l_run[1] += ls1;

        // ---- O rescale (only when not deferred) ----
        if (!defer) {
            const f32x4 a0 = *(const f32x4*)&alfw[quad * 4];
            const f32x4 a1 = *(const f32x4*)&alfw[quad * 4 + 16];
#pragma unroll
            for (int dt = 0; dt < 8; ++dt)
#pragma unroll
                for (int r = 0; r < 4; ++r) { O[0][dt][r] *= a0[r]; O[1][dt][r] *= a1[r]; }
        }

        // ---- PV: O += P(32x64) @ V(64x128), 32 MFMAs ----
#pragma unroll
        for (int ks = 0; ks < 2; ++ks) {
            const bf16x8 pa0 = *(const bf16x8*)(Pw + col * 72 + ks * 32 + quad * 8);
            const bf16x8 pa1 = *(const bf16x8*)(Pw + (col + 16) * 72 + ks * 32 + quad * 8);
#pragma unroll
            for (int dt = 0; dt < 8; ++dt) {
                const bf16x8 vf = *(const bf16x8*)(Vg + (dt * 16 + col) * 72 + ks * 32 + quad * 8);
                O[0][dt] = MFMA16(pa0, vf, O[0][dt]);
                O[1][dt] = MFMA16(pa1, vf, O[1][dt]);
            }
        }
    }

    // ---- merge: combine B-tile partials (A: keys >= 1088, B: keys < 1088) ----
    __syncthreads();  // all compute/LDS reads done; K/V buffers reusable
    float* mlA = (float*)(smem + 107520);  // [4][32][2]
    float* mlB = (float*)(smem + 108544);  // [4][32][2]
    if (g == 0) {
        float* Of = (float*)smem + gw * 4096;  // [32][128] raw O
        float* ml = mlA + gw * 64;
        if (quad == 0) {
            ml[2 * col]            = m_run[0]; ml[2 * col + 1]        = l_run[0];
            ml[2 * (col + 16)]     = m_run[1]; ml[2 * (col + 16) + 1] = l_run[1];
        }
#pragma unroll
        for (int pt = 0; pt < 2; ++pt)
#pragma unroll
            for (int dt = 0; dt < 8; ++dt)
#pragma unroll
                for (int r = 0; r < 4; ++r)
                    Of[(pt * 16 + quad * 4 + r) * 128 + dt * 16 + col] = O[pt][dt][r];
    }
    __syncthreads();
    if (g == 1) {
        float* Of = (float*)smem + gw * 4096;
        float* mA = mlA + gw * 64;
        float* mB = mlB + gw * 64;
        if (quad == 0) {
            mB[2 * col]            = m_run[0]; mB[2 * col + 1]        = l_run[0];
            mB[2 * (col + 16)]     = m_run[1]; mB[2 * (col + 16) + 1] = l_run[1];
        }
#pragma unroll
        for (int pt = 0; pt < 2; ++pt)
#pragma unroll
            for (int r = 0; r < 4; ++r) {
                const int row = pt * 16 + quad * 4 + r;
                const float mBv = mB[2 * row], lBv = mB[2 * row + 1];
                const float mAv = mA[2 * row], lAv = mA[2 * row + 1];
                const float m  = fmaxf(mAv, mBv);
                const float aB = exp2f(mBv - m);
                const float aA = exp2f(mAv - m);
                const float inv = 1.0f / (lBv * aB + lAv * aA);
                const int ig = w0 + row;
                unsigned short* op = ctx + ((size_t)(b * T_ + ig) * NQ_ + h) * H_;
#pragma unroll
                for (int dt = 0; dt < 8; ++dt)
                    op[dt * 16 + col] =
                        f2bf((O[pt][dt][r] * aB + Of[row * 128 + dt * 16 + col] * aA) * inv);
            }
    }
}

// ---------------------------------------------------------------------------
extern "C" void kernel_launch(void* const* d_in, const int* in_sizes, int n_in,
                              void* d_out, int out_size, void* d_ws, size_t ws_size,
                              hipStream_t stream) {
    const float* x    = (const float*)d_in[0];
    const float* Wq   = (const float*)d_in[1];
    const float* Wk   = (const float*)d_in[2];
    const float* Wv   = (const float*)d_in[3];
    const float* Wo   = (const float*)d_in[4];
    const float* qnw  = (const float*)d_in[5];
    const float* knw  = (const float*)d_in[6];
    const float* cosb = (const float*)d_in[7];
    const float* sinb = (const float*)d_in[8];
    // d_in[9] = attn_mask: exact causal tril(0/-1e9) -> implemented directly

    const int M = B_ * T_;  // 4096
    // ws layout (u16 offsets), 42 MB proven footprint:
    //   WqT/WkT/WvT [0,6291456) dead after QKV; ctx [0,8388608) aliases them
    //   q [8388608,16777216) (WoT aliases after attn); k; v
    unsigned short* ws  = (unsigned short*)d_ws;
    unsigned short* WqT = ws;
    unsigned short* WkT = WqT + (size_t)2048 * 2048;
    unsigned short* WvT = WkT + (size_t)512 * 2048;
    unsigned short* ctx = ws;
    unsigned short* q   = ws + (size_t)8388608;
    unsigned short* k   = ws + (size_t)16777216;
    unsigned short* v   = ws + (size_t)18874368;
    unsigned short* WoT = q;

    transpose_cvt<<<(2048 / 64) * (2048 / 64), 256, 0, stream>>>(Wq, WqT, 2048, 2048);
    transpose_cvt<<<(2048 / 64) * (512 / 64),  256, 0, stream>>>(Wk, WkT, 2048, 512);
    transpose_cvt<<<(2048 / 64) * (512 / 64),  256, 0, stream>>>(Wv, WvT, 2048, 512);

    gemm_bt<false, false><<<(M / 128) * (3072 / 128), 256, 0, stream>>>(
        (const void*)x, WqT, (void*)q, k, v, M, 3072, C_, 1);

    // Q pre-scaled by log2(e)/sqrt(128) for the exp2-domain softmax
    norm_rope<<<M * NQ_, 64, 0, stream>>>(q, qnw, cosb, sinb, NQ_, 0.12751743f);
    norm_rope<<<M * NKV_, 64, 0, stream>>>(k, knw, cosb, sinb, NKV_, 1.0f);

    flash_attn<<<256, 512, 0, stream>>>(q, k, v, ctx);

    transpose_cvt<<<(2048 / 64) * (2048 / 64), 256, 0, stream>>>(Wo, WoT, 2048, 2048);
    gemm_bt<true, true><<<(M / 128) * (C_ / 128), 256, 0, stream>>>(
        (const void*)ctx, WoT, d_out, nullptr, nullptr, M, C_, NQ_ * H_, 0);
}